// Round 1
// 502.081 us; speedup vs baseline: 1.6076x; 1.6076x over previous
//
#include <hip/hip_runtime.h>
#include <hip/hip_bf16.h>

// Problem constants
// B=2, M=384, N=96, D=512, J=640, C=1024
// a = enc @ w_audio + b_audio : [768][640]
// t = dec @ w_text  + b_text  : [192][640]
// out[r][c] = sum_j tanh(a[..][j] + t[..][j]) * w_join[j][c] + b_join[c]
//   r = (b*384+m)*96 + n  (73728 rows), c in [0,1024)

typedef float f32x4 __attribute__((ext_vector_type(4)));
typedef short short8 __attribute__((ext_vector_type(8)));

// Static device scratch — avoids any dependence on ws_size (fully rewritten
// by prep_kernel on every launch, so graph-replay/poisoning is safe).
__device__ float g_A[768 * 640];
__device__ float g_T[192 * 640];
__device__ short g_W2[80 * 1024 * 8];

__device__ __forceinline__ unsigned short f2bf(float f) {
    unsigned u = __float_as_uint(f);
    unsigned r = u + 0x7fffu + ((u >> 16) & 1u);   // RNE
    return (unsigned short)(r >> 16);
}

__device__ __forceinline__ float fast_tanh(float x) {
    x = fminf(fmaxf(x, -10.f), 10.f);
    float e2 = __expf(x * 2.0f);
    return 1.f - 2.f / (e2 + 1.f);
}

// ---------------------------------------------------------------------------
// Prep: blocks 0..239   -> projection GEMM, 4 rows each (192 A-blocks, 48 T)
//       blocks 240..495 -> pack w_join into bf16 W2[g][c][8], g=k/8
// v2: 2x block parallelism vs v1 (240 GEMM blocks instead of 120), float2
//     weight loads, unroll-4 k-loop for load pipelining.
// ---------------------------------------------------------------------------
__global__ __launch_bounds__(320) void prep_kernel(
    const float* __restrict__ enc, const float* __restrict__ dec,
    const float* __restrict__ w_audio, const float* __restrict__ b_audio,
    const float* __restrict__ w_text,  const float* __restrict__ b_text,
    const float* __restrict__ w_join)
{
    const int bid = blockIdx.x, tid = threadIdx.x;
    if (bid < 240) {
        const float *X, *W, *bias; float* O; int row0;
        if (bid < 192) { X = enc; W = w_audio; bias = b_audio; O = g_A; row0 = bid * 4; }
        else           { X = dec; W = w_text;  bias = b_text;  O = g_T; row0 = (bid - 192) * 4; }
        __shared__ float xs[4][512];
        for (int i = tid; i < 4 * 128; i += 320) {
            int r = i >> 7, q = i & 127;
            ((f32x4*)xs[r])[q] = ((const f32x4*)(X + (size_t)(row0 + r) * 512))[q];
        }
        __syncthreads();
        float acc[4][2] = {};
        const int j0 = tid * 2;                       // 2 adjacent cols per thread
        const float2* Wp = (const float2*)W;          // row stride = 320 float2
        #pragma unroll 4
        for (int k = 0; k < 512; ++k) {
            float2 wv = Wp[k * 320 + tid];
            #pragma unroll
            for (int r = 0; r < 4; ++r) {
                acc[r][0] = fmaf(xs[r][k], wv.x, acc[r][0]);
                acc[r][1] = fmaf(xs[r][k], wv.y, acc[r][1]);
            }
        }
        float2 bv = *(const float2*)(bias + j0);
        #pragma unroll
        for (int r = 0; r < 4; ++r) {
            float2 o = make_float2(acc[r][0] + bv.x, acc[r][1] + bv.y);
            *(float2*)(O + (row0 + r) * 640 + j0) = o;
        }
    } else {
        // pack w_join[640][1024] -> W2[(k/8)*1024 + c][8] bf16 (k fastest in group)
        int idx = (bid - 240) * 320 + tid;          // 0 .. 81919  (80*1024)
        int g = idx >> 10, c = idx & 1023;
        short8 v;
        #pragma unroll
        for (int j = 0; j < 8; ++j)
            v[j] = (short)f2bf(w_join[(g * 8 + j) * 1024 + c]);
        ((short8*)g_W2)[idx] = v;
    }
}

// ---------------------------------------------------------------------------
// Main fused join kernel: 1152 blocks x 256 threads (4 waves).
// Block = 64 GEMM-rows x 1024 cols. h (64x640 bf16) resident in LDS, swizzled.
// Wave tile = 64 rows x 64 cols per col-iter (4 col-iters of 256 cols).
// v2: MFMA operands SWAPPED (mfma(bf, af, .)) so the C layout is transposed:
//     each lane holds 4 consecutive output COLUMNS -> float4 stores.
//     Output stores are non-temporal (write-once stream; keep W2/A/T in L2).
// ---------------------------------------------------------------------------
__global__ __launch_bounds__(256, 2) void join_kernel(
    const float* __restrict__ b_join, // [1024]
    float* __restrict__ out)          // [73728][1024]
{
    __shared__ char hb[64 * 1280];    // 80 KiB: row stride 1280B, 16B groups XOR-swizzled
    const int tid = threadIdx.x;
    const int r0  = blockIdx.x * 64;

    // ---- Phase 1: h = tanh(a + t) -> LDS (bf16), once per element ----
    for (int e = tid; e < 64 * 160; e += 256) {
        int row = e / 160;
        int q   = e - row * 160;       // float4 index within row, j = 4q
        int r   = r0 + row;
        int arow = r / 96;                              // b*384 + m
        int trow = (r / 36864) * 96 + (r - arow * 96);  // b*96 + n
        int j = q * 4;
        f32x4 av = *(const f32x4*)(g_A + arow * 640 + j);
        f32x4 tv = *(const f32x4*)(g_T + trow * 640 + j);
        float h0 = fast_tanh(av[0] + tv[0]);
        float h1 = fast_tanh(av[1] + tv[1]);
        float h2 = fast_tanh(av[2] + tv[2]);
        float h3 = fast_tanh(av[3] + tv[3]);
        unsigned lo = (unsigned)f2bf(h0) | ((unsigned)f2bf(h1) << 16);
        unsigned hi = (unsigned)f2bf(h2) | ((unsigned)f2bf(h3) << 16);
        // group g = j/8 = q/2, swizzle g ^= (row&7); half-group select = q&1
        unsigned off = row * 1280 + (((unsigned)((q >> 1) ^ (row & 7))) << 4) + (q & 1) * 8;
        *(uint2*)(hb + off) = make_uint2(lo, hi);
    }
    __syncthreads();

    // ---- Phase 2: MFMA GEMM, no barriers in K-loop ----
    const int lane = tid & 63;
    const int wave = tid >> 6;     // 0..3
    const int l15  = lane & 15;
    const int quad = lane >> 4;    // 0..3

    for (int ct = 0; ct < 4; ++ct) {
        const int colw = ct * 256 + wave * 64;
        f32x4 acc[4][4] = {};
        for (int kb = 0; kb < 640; kb += 32) {
            const int g = (kb >> 3) + quad;       // 16B-group index along K
            short8 af[4], bf[4];
            #pragma unroll
            for (int mt = 0; mt < 4; ++mt) {
                int row = mt * 16 + l15;
                af[mt] = *(const short8*)(hb + row * 1280 + ((unsigned)(g ^ (row & 7)) << 4));
            }
            #pragma unroll
            for (int nt = 0; nt < 4; ++nt) {
                int col = colw + nt * 16 + l15;
                bf[nt] = *(const short8*)(g_W2 + ((size_t)g * 1024 + col) * 8);
            }
            // Swapped operands: D = (W2-frag as A) * (h-frag as B)
            //  -> lane l, reg rg holds out[row = mt*16 + (l&15)]
            //                             [col = colw + nt*16 + (l>>4)*4 + rg]
            #pragma unroll
            for (int mt = 0; mt < 4; ++mt)
                #pragma unroll
                for (int nt = 0; nt < 4; ++nt)
                    acc[mt][nt] = __builtin_amdgcn_mfma_f32_16x16x32_bf16(
                        bf[nt], af[mt], acc[mt][nt], 0, 0, 0);
        }
        // epilogue: add b_join, store fp32 as float4 non-temporal.
        // mt-outer/nt-inner: both 64B halves of each 128B line are written by
        // adjacent instructions -> full-line dirty, no partial evictions.
        f32x4 bj[4];
        #pragma unroll
        for (int nt = 0; nt < 4; ++nt)
            bj[nt] = *(const f32x4*)(b_join + colw + nt * 16 + quad * 4);
        #pragma unroll
        for (int mt = 0; mt < 4; ++mt) {
            float* orow = out + (size_t)(r0 + mt * 16 + l15) * 1024;
            #pragma unroll
            for (int nt = 0; nt < 4; ++nt) {
                int c4 = colw + nt * 16 + quad * 4;
                f32x4 v = acc[mt][nt] + bj[nt];
                __builtin_nontemporal_store(v, (f32x4*)(orow + c4));
            }
        }
    }
}

// ---------------------------------------------------------------------------
extern "C" void kernel_launch(void* const* d_in, const int* in_sizes, int n_in,
                              void* d_out, int out_size, void* d_ws, size_t ws_size,
                              hipStream_t stream) {
    const float* enc     = (const float*)d_in[0];
    const float* dec     = (const float*)d_in[1];
    const float* w_audio = (const float*)d_in[2];
    const float* b_audio = (const float*)d_in[3];
    const float* w_text  = (const float*)d_in[4];
    const float* b_text  = (const float*)d_in[5];
    const float* w_join  = (const float*)d_in[6];
    const float* b_join  = (const float*)d_in[7];
    float* out = (float*)d_out;

    prep_kernel<<<dim3(496), dim3(320), 0, stream>>>(
        enc, dec, w_audio, b_audio, w_text, b_text, w_join);
    join_kernel<<<dim3(1152), dim3(256), 0, stream>>>(b_join, out);
}